// Round 14
// baseline (252.238 us; speedup 1.0000x reference)
//
#include <hip/hip_runtime.h>

typedef __attribute__((ext_vector_type(8))) _Float16 f16x8;
typedef __attribute__((ext_vector_type(4))) _Float16 f16x4;
typedef __attribute__((ext_vector_type(4))) float f32x4;
typedef __attribute__((address_space(1))) const char gc_char;
typedef __attribute__((address_space(3))) char ls_char;

#define MFMA(a, b, c) __builtin_amdgcn_mfma_f32_16x16x32_f16((a), (b), (c), 0, 0, 0)
#define FENCE() asm volatile("" ::: "memory")
#define BARRIER() do { FENCE(); __builtin_amdgcn_s_barrier(); FENCE(); } while (0)
#define VMW(n) asm volatile("s_waitcnt vmcnt(" #n ")" ::: "memory")

static constexpr int SEQ = 4096;
static constexpr int EMB = 512;
static constexpr float QSCALE = 0.04419417382415922f; // 1/sqrt(512)

__device__ __forceinline__ void gl_lds16(const void* g, void* l) {
    __builtin_amdgcn_global_load_lds((gc_char*)g, (ls_char*)l, 16, 0, 0);
}

// ---------------- fused prep: cast x + LDS-tiled transpose-cast both W ----------------
__global__ void k_prep(const float* __restrict__ x, _Float16* __restrict__ xb,
                       const float* __restrict__ Wq, _Float16* __restrict__ WqT,
                       const float* __restrict__ Wo, _Float16* __restrict__ WoT) {
    const int bid = blockIdx.x, tid = threadIdx.x;
    if (bid < 4096) {
        long i = (long)bid * 256 + tid;
        const float4* p = (const float4*)x + i * 2;
        float4 a = p[0], b = p[1];
        f16x8 v;
        v[0] = (_Float16)a.x; v[1] = (_Float16)a.y; v[2] = (_Float16)a.z; v[3] = (_Float16)a.w;
        v[4] = (_Float16)b.x; v[5] = (_Float16)b.y; v[6] = (_Float16)b.z; v[7] = (_Float16)b.w;
        *(f16x8*)(xb + i * 8) = v;
    } else {
        __shared__ float Ls[64][65];
        int t = bid - 4096;
        const float* W; _Float16* WT; int N, k0, n0;
        if (t < 192) { W = Wq; WT = WqT; N = 1536; k0 = (t & 7) * 64; n0 = (t >> 3) * 64; }
        else { t -= 192; W = Wo; WT = WoT; N = 512; k0 = (t & 7) * 64; n0 = (t >> 3) * 64; }
        int c = tid & 63, r4 = tid >> 6;
#pragma unroll
        for (int i = 0; i < 16; ++i) {
            int row = i * 4 + r4;
            Ls[row][c] = W[(long)(k0 + row) * N + n0 + c];
        }
        __syncthreads();
#pragma unroll
        for (int i = 0; i < 16; ++i) {
            int row = i * 4 + r4;
            WT[(long)(n0 + row) * 512 + k0 + c] = (_Float16)Ls[c][row];
        }
    }
}

// ================= QKV GEMM v2: 256x256 tile, BK=32, per-wave 128x128 =================
// 256 thr = 4 waves (2x2). acc[8][8]. LDS 2 x 32KB dbuf -> 2 blocks/CU. Grid 384.
// Rationale: per-wave 64x64 gives 32 MFMA-FLOP per LDS-byte (< 48 needed) -> LDS-BW-bound.
// 128x128/wave gives 64 FLOP/B -> MFMA-bound. 2-phase counted-vmcnt loop (T3-minimum).
__launch_bounds__(256, 2) __global__
void k_gemm_qkv(const _Float16* __restrict__ A, const _Float16* __restrict__ BT,
                const float* __restrict__ bias,
                _Float16* __restrict__ Qo, _Float16* __restrict__ Ko, _Float16* __restrict__ VT) {
    extern __shared__ __align__(16) char smem[];
    const int tid = threadIdx.x, lane = tid & 63, w = tid >> 6, g = lane >> 4, f = lane & 15;
    const int wr = w >> 1, wc = w & 1;
    const int bid = blockIdx.x;
    const int swz = (bid & 7) * 48 + (bid >> 3); // bijective XCD swizzle (384 % 8 == 0)
    const int brow = swz / 6, bcol = swz - brow * 6;
    const long row0 = (long)brow * 256;
    const int col0 = bcol * 256;
    const char* Abase = (const char*)A + row0 * 1024;
    const char* Bbase = (const char*)BT + (long)col0 * 1024;

    f32x4 acc[8][8] = {};

    // stage: A rows / B cols, 64B per row (BK=32), 4 chunks; swizzle ch = gd ^ ((row>>1)&3)
    auto stage = [&](char* dst, int kt) {
#pragma unroll
        for (int it = 0; it < 4; ++it) {
            int s = it * 256 + tid;
            int row = s >> 2, ch = s & 3;
            int gd = ch ^ ((row >> 1) & 3);
            gl_lds16(Abase + (long)row * 1024 + kt * 64 + gd * 16, dst + s * 16);
        }
#pragma unroll
        for (int it = 0; it < 4; ++it) {
            int s = it * 256 + tid;
            int row = s >> 2, ch = s & 3;
            int gd = ch ^ ((row >> 1) & 3);
            gl_lds16(Bbase + (long)row * 1024 + kt * 64 + gd * 16, dst + 16384 + s * 16);
        }
    };

    stage(smem, 0); // prologue: 8 loads in flight

    for (int kt = 0; kt < 16; ++kt) {
        const char* cur = smem + (kt & 1) * 32768;
        char* nxt = smem + ((kt + 1) & 1) * 32768;
        if (kt < 15) { stage(nxt, kt + 1); VMW(8); } else { VMW(0); }
        BARRIER();
        f16x8 a[8], b[8];
#pragma unroll
        for (int mi = 0; mi < 8; ++mi) {
            int rr = wr * 128 + mi * 16 + f;
            a[mi] = *(const f16x8*)(cur + rr * 64 + ((g ^ ((rr >> 1) & 3)) << 4));
        }
#pragma unroll
        for (int ni = 0; ni < 8; ++ni) {
            int cc = wc * 128 + ni * 16 + f;
            b[ni] = *(const f16x8*)(cur + 16384 + cc * 64 + ((g ^ ((cc >> 1) & 3)) << 4));
        }
        __builtin_amdgcn_s_setprio(1);
#pragma unroll
        for (int mi = 0; mi < 8; ++mi)
#pragma unroll
            for (int ni = 0; ni < 8; ++ni)
                acc[mi][ni] = MFMA(a[mi], b[ni], acc[mi][ni]);
        __builtin_amdgcn_s_setprio(0);
        BARRIER();
    }

    float bv[8];
#pragma unroll
    for (int ni = 0; ni < 8; ++ni) bv[ni] = bias[col0 + wc * 128 + ni * 16 + f];

    if (col0 >= 1024) {
        // V: transposed epilogue, 2 passes of 128 k-rows through 64KB LDS T[e 256][k 128]
        _Float16* vt = VT + ((long)(row0 >> 12) * 512 + (col0 - 1024)) * 4096 + (row0 & 4095);
#pragma unroll
        for (int p = 0; p < 2; ++p) {
            if (p) BARRIER();
            if (wr == p) {
#pragma unroll
                for (int mi = 0; mi < 8; ++mi)
#pragma unroll
                    for (int ni = 0; ni < 8; ++ni) {
                        int k0l = mi * 16 + g * 4;            // local k
                        int e = wc * 128 + ni * 16 + f;       // local e
                        f16x4 v4;
#pragma unroll
                        for (int j = 0; j < 4; ++j) v4[j] = (_Float16)(acc[mi][ni][j] + bv[ni]);
                        *(f16x4*)(smem + e * 256 + ((k0l * 2) ^ ((e & 7) << 4))) = v4;
                    }
            }
            BARRIER();
#pragma unroll
            for (int it = 0; it < 16; ++it) {
                int slot = it * 256 + tid;
                int e = slot >> 4, ch = slot & 15;
                f16x8 v = *(const f16x8*)(smem + e * 256 + ((ch * 16) ^ ((e & 7) << 4)));
                *(f16x8*)(vt + (long)e * 4096 + p * 128 + ch * 8) = v;
            }
        }
    } else {
        // Q/K: rotation-swizzle row-major epilogue, 2 passes of 128 rows
        const float sc = (col0 < 512) ? QSCALE : 1.0f;
        _Float16* dst = (col0 < 512) ? Qo : Ko;
        int cofs = (col0 < 512) ? col0 : col0 - 512;
#pragma unroll
        for (int p = 0; p < 2; ++p) {
            if (p) BARRIER();
            if (wr == p) {
#pragma unroll
                for (int mi = 0; mi < 8; ++mi)
#pragma unroll
                    for (int ni = 0; ni < 8; ++ni)
#pragma unroll
                        for (int j = 0; j < 4; ++j) {
                            int r = mi * 16 + g * 4 + j;      // local row in pass
                            int c = wc * 128 + ni * 16 + f;   // local col (256)
                            float v = (acc[mi][ni][j] + bv[ni]) * sc;
                            int pc = ((c >> 3) + ((r >> 2) & 7) * 2) & 31;
                            *(_Float16*)(smem + r * 512 + pc * 16 + (c & 7) * 2) = (_Float16)v;
                        }
            }
            BARRIER();
#pragma unroll
            for (int it = 0; it < 16; ++it) {
                int slot = it * 256 + tid;
                int r = slot >> 5, ch = slot & 31;
                int pc = (ch + ((r >> 2) & 7) * 2) & 31;
                f16x8 v = *(const f16x8*)(smem + r * 512 + pc * 16);
                *(f16x8*)(dst + (row0 + p * 128 + r) * 512 + cofs + ch * 8) = v;
            }
        }
    }
}

// ======= fused attention + out-proj (r13, unchanged) =======
__launch_bounds__(512, 1) __global__
void k_attn(const _Float16* __restrict__ Qb, const _Float16* __restrict__ Kb,
            const _Float16* __restrict__ VT, const _Float16* __restrict__ WoT,
            const float* __restrict__ bout, float* __restrict__ Out) {
    extern __shared__ __align__(16) char smem[];
    char* buf[2] = { smem, smem + 49152 };
    char* Pl = smem + 98304;
    float* Mp = (float*)(smem + 123904);
    float* Lp = (float*)(smem + 124928);

    const int tid = threadIdx.x, w = tid >> 6, lane = tid & 63, g = lane >> 4, f = lane & 15;
    const int rh = w >> 2, kh = w & 3;
    const int bid = blockIdx.x;
    const int swzb = (bid & 7) * 32 + (bid >> 3);
    const int b = swzb >> 6, qt = swzb & 63;
    const int q0 = qt * 64, kbase = q0 - 64;
    const long bofs = (long)b * SEQ;

    f16x8 qf[2][16];
#pragma unroll
    for (int mt = 0; mt < 2; ++mt) {
        const _Float16* qr = Qb + (bofs + q0 + rh * 32 + mt * 16 + f) * EMB + g * 8;
#pragma unroll
        for (int ks = 0; ks < 16; ++ks) qf[mt][ks] = *(const f16x8*)(qr + ks * 32);
    }

    auto stageK = [&](int ec, char* dst) {
#pragma unroll
        for (int it = 0; it < 6; ++it) {
            int slot = it * 512 + tid;
            int r = slot >> 4, c = slot & 15;
            int cs = c ^ (r & 7);
            int key = min(max(kbase + r, 0), SEQ - 1);
            gl_lds16(Kb + (bofs + key) * EMB + ec * 128 + cs * 8, dst + slot * 16);
        }
    };
    auto stageVT = [&](int ec, char* dst) {
#pragma unroll
        for (int it = 0; it < 6; ++it) {
            int slot = it * 512 + tid;
            int r = slot / 24, c = slot - r * 24;
            int cs = c ^ (r & 7);
            int k0 = min(max(kbase + cs * 8, 0), SEQ - 8);
            gl_lds16(VT + ((long)b * 512 + ec * 128 + r) * 4096 + k0, dst + slot * 16);
        }
    };

    f32x4 sacc[2][3] = {};
    stageK(0, buf[0]);
    for (int ec = 0; ec < 4; ++ec) {
        if (ec < 3) stageK(ec + 1, buf[(ec + 1) & 1]);
        else stageVT(0, buf[0]);
        VMW(6);
        BARRIER();
        const char* kb = buf[ec & 1];
#pragma unroll
        for (int kk = 0; kk < 4; ++kk) {
#pragma unroll
            for (int t = 0; t < 3; ++t) {
                int n = kh * 48 + t * 16 + f;
                f16x8 bf = *(const f16x8*)(kb + n * 256 + (((kk * 4 + g) ^ (n & 7)) << 4));
#pragma unroll
                for (int mt = 0; mt < 2; ++mt)
                    sacc[mt][t] = MFMA(qf[mt][ec * 4 + kk], bf, sacc[mt][t]);
            }
        }
        BARRIER();
    }

    float m[2][4] = {{-3e30f, -3e30f, -3e30f, -3e30f}, {-3e30f, -3e30f, -3e30f, -3e30f}};
    float l[2][4] = {};
#pragma unroll
    for (int mt = 0; mt < 2; ++mt)
#pragma unroll
        for (int t = 0; t < 3; ++t) {
            int key = kbase + kh * 48 + t * 16 + f;
            bool kv = (key >= 0) && (key < SEQ);
#pragma unroll
            for (int j = 0; j < 4; ++j) {
                int d = key - (q0 + rh * 32 + mt * 16 + g * 4 + j);
                bool valid = kv && (d >= -64) && (d <= 64);
                float s = valid ? sacc[mt][t][j] : -3e30f;
                sacc[mt][t][j] = s;
                m[mt][j] = fmaxf(m[mt][j], s);
            }
        }
#pragma unroll
    for (int mt = 0; mt < 2; ++mt)
#pragma unroll
        for (int j = 0; j < 4; ++j) {
            m[mt][j] = fmaxf(m[mt][j], __shfl_xor(m[mt][j], 1));
            m[mt][j] = fmaxf(m[mt][j], __shfl_xor(m[mt][j], 2));
            m[mt][j] = fmaxf(m[mt][j], __shfl_xor(m[mt][j], 4));
            m[mt][j] = fmaxf(m[mt][j], __shfl_xor(m[mt][j], 8));
        }
    if (f == 0) {
#pragma unroll
        for (int mt = 0; mt < 2; ++mt)
#pragma unroll
            for (int j = 0; j < 4; ++j)
                Mp[kh * 64 + rh * 32 + mt * 16 + g * 4 + j] = m[mt][j];
    }
    __syncthreads();
#pragma unroll
    for (int mt = 0; mt < 2; ++mt)
#pragma unroll
        for (int j = 0; j < 4; ++j) {
            int r = rh * 32 + mt * 16 + g * 4 + j;
            m[mt][j] = fmaxf(fmaxf(Mp[r], Mp[64 + r]), fmaxf(Mp[128 + r], Mp[192 + r]));
        }
#pragma unroll
    for (int mt = 0; mt < 2; ++mt)
#pragma unroll
        for (int t = 0; t < 3; ++t)
#pragma unroll
            for (int j = 0; j < 4; ++j) {
                float p = __expf(sacc[mt][t][j] - m[mt][j]);
                sacc[mt][t][j] = p;
                l[mt][j] += p;
            }
#pragma unroll
    for (int mt = 0; mt < 2; ++mt)
#pragma unroll
        for (int j = 0; j < 4; ++j) {
            l[mt][j] += __shfl_xor(l[mt][j], 1);
            l[mt][j] += __shfl_xor(l[mt][j], 2);
            l[mt][j] += __shfl_xor(l[mt][j], 4);
            l[mt][j] += __shfl_xor(l[mt][j], 8);
        }
    if (f == 0) {
#pragma unroll
        for (int mt = 0; mt < 2; ++mt)
#pragma unroll
            for (int j = 0; j < 4; ++j)
                Lp[kh * 64 + rh * 32 + mt * 16 + g * 4 + j] = l[mt][j];
    }
#pragma unroll
    for (int mt = 0; mt < 2; ++mt)
#pragma unroll
        for (int t = 0; t < 3; ++t)
#pragma unroll
            for (int j = 0; j < 4; ++j)
                *(_Float16*)(Pl + (rh * 32 + mt * 16 + g * 4 + j) * 400 +
                             (kh * 48 + t * 16 + f) * 2) = (_Float16)sacc[mt][t][j];
    __syncthreads();

    float rl[2][4];
#pragma unroll
    for (int mt = 0; mt < 2; ++mt)
#pragma unroll
        for (int j = 0; j < 4; ++j) {
            int r = rh * 32 + mt * 16 + g * 4 + j;
            rl[mt][j] = 1.0f / (Lp[r] + Lp[64 + r] + Lp[128 + r] + Lp[192 + r]);
        }

    f16x8 pf[2][6];
#pragma unroll
    for (int mt = 0; mt < 2; ++mt)
#pragma unroll
        for (int kc = 0; kc < 6; ++kc)
            pf[mt][kc] = *(const f16x8*)(Pl + (rh * 32 + mt * 16 + f) * 400 + kc * 64 + g * 16);

    f32x4 oacc[4][2][2] = {};
    for (int ec = 0; ec < 4; ++ec) {
        if (ec < 3) stageVT(ec + 1, buf[(ec + 1) & 1]);
        if (ec > 0) { if (ec < 3) { VMW(6); } else { VMW(0); } }
        BARRIER();
        const char* vb = buf[ec & 1];
#pragma unroll
        for (int kc = 0; kc < 6; ++kc) {
#pragma unroll
            for (int nt = 0; nt < 2; ++nt) {
                int e = kh * 32 + nt * 16 + f;
                f16x8 vf = *(const f16x8*)(vb + e * 384 + (((kc * 4 + g) ^ (e & 7)) << 4));
#pragma unroll
                for (int mt = 0; mt < 2; ++mt)
                    oacc[ec][mt][nt] = MFMA(pf[mt][kc], vf, oacc[ec][mt][nt]);
            }
        }
        BARRIER();
    }

    __syncthreads();
    char* att = smem;
    char* wb0 = smem + 65536;
    char* wb1 = smem + 98304;

    auto stageW = [&](int u, char* dst) {
#pragma unroll
        for (int i = 0; i < 4; ++i) {
            int s = i * 512 + tid;
            int col = s >> 2, ch = s & 3;
            int gd = (ch - (col >> 1)) & 3;
            gl_lds16(WoT + (long)col * 512 + u * 32 + gd * 8, dst + s * 16);
        }
    };
    stageW(0, wb0);
    stageW(1, wb1);
#pragma unroll
    for (int ec = 0; ec < 4; ++ec)
#pragma unroll
        for (int mt = 0; mt < 2; ++mt)
#pragma unroll
            for (int nt = 0; nt < 2; ++nt)
#pragma unroll
                for (int j = 0; j < 4; ++j) {
                    int row = rh * 32 + mt * 16 + g * 4 + j;
                    int col = ec * 128 + kh * 32 + nt * 16 + f;
                    *(_Float16*)(att + row * 1024 + ((col * 2) ^ ((row & 7) << 4))) =
                        (_Float16)(oacc[ec][mt][nt][j] * rl[mt][j]);
                }
    __syncthreads();

    float bv2[8];
#pragma unroll
    for (int nt = 0; nt < 8; ++nt) bv2[nt] = bout[kh * 128 + nt * 16 + f];

    f32x4 acc2[2][8] = {};
    for (int u = 0; u < 16; ++u) {
        const char* wcur = (u & 1) ? wb1 : wb0;
        f16x8 a2[2];
#pragma unroll
        for (int mt = 0; mt < 2; ++mt) {
            int row = rh * 32 + mt * 16 + f;
            a2[mt] = *(const f16x8*)(att + row * 1024 + ((u * 64 + g * 16) ^ ((row & 7) << 4)));
        }
        __builtin_amdgcn_s_setprio(1);
#pragma unroll
        for (int nt = 0; nt < 8; ++nt) {
            int col = kh * 128 + nt * 16 + f;
            f16x8 b2 = *(const f16x8*)(wcur + col * 64 + (((g + (col >> 1)) & 3) << 4));
#pragma unroll
            for (int mt = 0; mt < 2; ++mt)
                acc2[mt][nt] = MFMA(a2[mt], b2, acc2[mt][nt]);
        }
        __builtin_amdgcn_s_setprio(0);
        BARRIER();
        if (u + 2 < 16) {
            stageW(u + 2, (u & 1) ? wb1 : wb0);
            VMW(4);
        } else {
            VMW(0);
        }
        BARRIER();
    }

#pragma unroll
    for (int mt = 0; mt < 2; ++mt)
#pragma unroll
        for (int nt = 0; nt < 8; ++nt) {
            long r0 = bofs + q0 + rh * 32 + mt * 16 + g * 4;
            int c = kh * 128 + nt * 16 + f;
#pragma unroll
            for (int j = 0; j < 4; ++j)
                Out[(r0 + j) * 512 + c] = acc2[mt][nt][j] + bv2[nt];
        }
}

extern "C" void kernel_launch(void* const* d_in, const int* in_sizes, int n_in,
                              void* d_out, int out_size, void* d_ws, size_t ws_size,
                              hipStream_t stream) {
    const float* x     = (const float*)d_in[0];
    const float* W_qkv = (const float*)d_in[1];
    const float* b_qkv = (const float*)d_in[2];
    const float* W_out = (const float*)d_in[3];
    const float* b_out = (const float*)d_in[4];

    char* ws = (char*)d_ws;
    _Float16* xb    = (_Float16*)(ws);                         // 16 MiB
    _Float16* WqkvT = (_Float16*)(ws + 16777216);              // 1.5 MiB
    _Float16* WoutT = (_Float16*)(ws + 16777216 + 1572864);    // 0.5 MiB
    _Float16* Qb    = (_Float16*)(ws + 18874368);              // 16 MiB
    _Float16* Kb    = (_Float16*)(ws + 18874368 + 16777216);   // 16 MiB
    _Float16* VT    = (_Float16*)(ws + 18874368 + 33554432);   // 16 MiB [b][e][k]
    float* out = (float*)d_out;

    (void)hipFuncSetAttribute((const void*)k_gemm_qkv,
                              hipFuncAttributeMaxDynamicSharedMemorySize, 65536);
    (void)hipFuncSetAttribute((const void*)k_attn,
                              hipFuncAttributeMaxDynamicSharedMemorySize, 131072);

    k_prep<<<4352, 256, 0, stream>>>(x, xb, W_qkv, WqkvT, W_out, WoutT);
    k_gemm_qkv<<<384, 256, 65536, stream>>>(xb, WqkvT, b_qkv, Qb, Kb, VT);
    k_attn<<<256, 512, 131072, stream>>>(Qb, Kb, VT, WoutT, b_out, out);
}

// Round 15
// 79.800 us; speedup vs baseline: 3.1609x; 3.1609x over previous
//
#include <hip/hip_runtime.h>

typedef __attribute__((ext_vector_type(8))) _Float16 f16x8;
typedef __attribute__((ext_vector_type(4))) _Float16 f16x4;
typedef __attribute__((ext_vector_type(4))) float f32x4;
typedef __attribute__((address_space(1))) const char gc_char;
typedef __attribute__((address_space(3))) char ls_char;

#define MFMA(a, b, c) __builtin_amdgcn_mfma_f32_16x16x32_f16((a), (b), (c), 0, 0, 0)
#define FENCE() asm volatile("" ::: "memory")
#define BARRIER() do { FENCE(); __builtin_amdgcn_s_barrier(); FENCE(); } while (0)
#define VMW(n) asm volatile("s_waitcnt vmcnt(" #n ")" ::: "memory")

static constexpr int SEQ = 4096;
static constexpr int EMB = 512;
static constexpr float QSCALE = 0.04419417382415922f; // 1/sqrt(512)

__device__ __forceinline__ void gl_lds16(const void* g, void* l) {
    __builtin_amdgcn_global_load_lds((gc_char*)g, (ls_char*)l, 16, 0, 0);
}

// ---------------- fused prep: cast x + LDS-tiled transpose-cast both W ----------------
__global__ void k_prep(const float* __restrict__ x, _Float16* __restrict__ xb,
                       const float* __restrict__ Wq, _Float16* __restrict__ WqT,
                       const float* __restrict__ Wo, _Float16* __restrict__ WoT) {
    const int bid = blockIdx.x, tid = threadIdx.x;
    if (bid < 4096) {
        long i = (long)bid * 256 + tid;
        const float4* p = (const float4*)x + i * 2;
        float4 a = p[0], b = p[1];
        f16x8 v;
        v[0] = (_Float16)a.x; v[1] = (_Float16)a.y; v[2] = (_Float16)a.z; v[3] = (_Float16)a.w;
        v[4] = (_Float16)b.x; v[5] = (_Float16)b.y; v[6] = (_Float16)b.z; v[7] = (_Float16)b.w;
        *(f16x8*)(xb + i * 8) = v;
    } else {
        __shared__ float Ls[64][65];
        int t = bid - 4096;
        const float* W; _Float16* WT; int N, k0, n0;
        if (t < 192) { W = Wq; WT = WqT; N = 1536; k0 = (t & 7) * 64; n0 = (t >> 3) * 64; }
        else { t -= 192; W = Wo; WT = WoT; N = 512; k0 = (t & 7) * 64; n0 = (t >> 3) * 64; }
        int c = tid & 63, r4 = tid >> 6;
#pragma unroll
        for (int i = 0; i < 16; ++i) {
            int row = i * 4 + r4;
            Ls[row][c] = W[(long)(k0 + row) * N + n0 + c];
        }
        __syncthreads();
#pragma unroll
        for (int i = 0; i < 16; ++i) {
            int row = i * 4 + r4;
            WT[(long)(n0 + row) * 512 + k0 + c] = (_Float16)Ls[c][row];
        }
    }
}

// ================= 128x256 tile, BK=64, 4-phase counted-vmcnt QKV GEMM =================
__launch_bounds__(512, 1) __global__
void k_gemm_qkv(const _Float16* __restrict__ A, const _Float16* __restrict__ BT,
                const float* __restrict__ bias,
                _Float16* __restrict__ Qo, _Float16* __restrict__ Ko, _Float16* __restrict__ VT) {
    extern __shared__ __align__(16) char smem[];
    const int tid = threadIdx.x, lane = tid & 63, w = tid >> 6, g = lane >> 4, f = lane & 15;
    const int wrow = w >> 2, wcol = w & 3;
    const int bid = blockIdx.x;
    const int swz = (bid & 7) * 96 + (bid >> 3);
    const int brow = swz / 6, bcol = swz - brow * 6;
    const long row0 = (long)brow * 128;
    const int col0 = bcol * 256;
    const char* Abase = (const char*)A + row0 * 1024;
    const char* Bbase = (const char*)BT + (long)col0 * 1024;

    f32x4 acc[4][4] = {};
    f16x8 a[2][2], breg[2][2][2];

    auto stageA = [&](int h, char* dst, int kt) {
        int rr = tid >> 3;
        int ch = (tid & 7) ^ (rr & 7);
        int grow = h * 32 + (rr & 31) + (rr >> 5) * 64;
        gl_lds16(Abase + (long)grow * 1024 + kt * 128 + ch * 16, dst + h * 8192 + tid * 16);
    };
    auto stageB = [&](int h, char* dst, int kt) {
#pragma unroll
        for (int it = 0; it < 2; ++it) {
            int s = it * 512 + tid;
            int cc = s >> 3;
            int ch = (s & 7) ^ (cc & 7);
            int gcol = h * 32 + (cc & 31) + (cc >> 5) * 64;
            gl_lds16(Bbase + (long)gcol * 1024 + kt * 128 + ch * 16,
                     dst + 16384 + h * 16384 + s * 16);
        }
    };
    auto ldA = [&](const char* buf, int mh) {
#pragma unroll
        for (int mi = 0; mi < 2; ++mi)
#pragma unroll
            for (int ks = 0; ks < 2; ++ks) {
                int rr = wrow * 32 + mi * 16 + f;
                int cl = ks * 4 + g;
                a[mi][ks] = *(const f16x8*)(buf + mh * 8192 + rr * 128 + ((cl ^ (rr & 7)) << 4));
            }
    };
    auto ldB = [&](const char* buf, int nh) {
#pragma unroll
        for (int ni = 0; ni < 2; ++ni)
#pragma unroll
            for (int ks = 0; ks < 2; ++ks) {
                int cc = wcol * 32 + ni * 16 + f;
                int cl = ks * 4 + g;
                breg[nh][ni][ks] =
                    *(const f16x8*)(buf + 16384 + nh * 16384 + cc * 128 + ((cl ^ (cc & 7)) << 4));
            }
    };
    auto mfma8 = [&](int mh, int nh) {
        __builtin_amdgcn_s_setprio(1);
#pragma unroll
        for (int mi = 0; mi < 2; ++mi)
#pragma unroll
            for (int ni = 0; ni < 2; ++ni)
#pragma unroll
                for (int ks = 0; ks < 2; ++ks)
                    acc[mh * 2 + mi][nh * 2 + ni] =
                        MFMA(a[mi][ks], breg[nh][ni][ks], acc[mh * 2 + mi][nh * 2 + ni]);
        __builtin_amdgcn_s_setprio(0);
    };

    stageB(0, smem, 0);
    stageA(0, smem, 0); stageA(1, smem, 0);
    stageB(1, smem, 0);
    VMW(3);
    BARRIER();

    for (int kt = 0; kt < 8; ++kt) {
        const char* cur = smem + (kt & 1) * 49152;
        char* nxt = smem + ((kt + 1) & 1) * 49152;
        const bool last = (kt == 7);
        ldA(cur, 0); ldB(cur, 0);
        if (!last) stageB(0, nxt, kt + 1);
        BARRIER();
        mfma8(0, 0);
        if (!last) { VMW(2); } else { VMW(0); }
        BARRIER();
        ldB(cur, 1);
        if (!last) { stageA(0, nxt, kt + 1); stageA(1, nxt, kt + 1); }
        BARRIER();
        mfma8(0, 1);
        BARRIER();
        ldA(cur, 1);
        if (!last) stageB(1, nxt, kt + 1);
        BARRIER();
        mfma8(1, 0);
        BARRIER();
        mfma8(1, 1);
        if (!last) { VMW(3); }
        BARRIER();
    }

    float bv[4];
#pragma unroll
    for (int ni = 0; ni < 4; ++ni) bv[ni] = bias[col0 + wcol * 64 + ni * 16 + f];

    if (col0 >= 1024) {
#pragma unroll
        for (int mi = 0; mi < 4; ++mi)
#pragma unroll
            for (int ni = 0; ni < 4; ++ni) {
                int r0 = wrow * 64 + mi * 16 + g * 4;
                int c = wcol * 64 + ni * 16 + f;
                f16x4 v4;
#pragma unroll
                for (int j = 0; j < 4; ++j) v4[j] = (_Float16)(acc[mi][ni][j] + bv[ni]);
                *(f16x4*)(smem + c * 256 + ((r0 * 2) ^ ((c & 7) << 4))) = v4;
            }
        __syncthreads();
        int bb = (int)(row0 >> 12);
        _Float16* vt = VT + ((long)bb * 512 + (col0 - 1024)) * 4096 + (row0 & 4095);
#pragma unroll
        for (int it = 0; it < 8; ++it) {
            int slot = it * 512 + tid;
            int e = slot >> 4, ch = slot & 15;
            f16x8 v = *(const f16x8*)(smem + e * 256 + ((ch * 16) ^ ((e & 7) << 4)));
            *(f16x8*)(vt + (long)e * 4096 + ch * 8) = v;
        }
    } else {
        const float sc = (col0 < 512) ? QSCALE : 1.0f;
#pragma unroll
        for (int mi = 0; mi < 4; ++mi)
#pragma unroll
            for (int ni = 0; ni < 4; ++ni)
#pragma unroll
                for (int j = 0; j < 4; ++j) {
                    int r = wrow * 64 + mi * 16 + g * 4 + j;
                    int c = wcol * 64 + ni * 16 + f;
                    float v = (acc[mi][ni][j] + bv[ni]) * sc;
                    int pc = ((c >> 3) + ((r >> 2) & 7) * 2) & 31;
                    *(_Float16*)(smem + r * 512 + pc * 16 + (c & 7) * 2) = (_Float16)v;
                }
        __syncthreads();
        _Float16* dst = (col0 < 512) ? Qo : Ko;
        int cofs = (col0 < 512) ? col0 : col0 - 512;
#pragma unroll
        for (int it = 0; it < 8; ++it) {
            int slot = it * 512 + tid;
            int r = slot >> 5, ch = slot & 31;
            int pc = (ch + ((r >> 2) & 7) * 2) & 31;
            f16x8 v = *(const f16x8*)(smem + r * 512 + pc * 16);
            *(f16x8*)(dst + (row0 + r) * 512 + cofs + ch * 8) = v;
        }
    }
}

// ======= fused attention + out-proj: QBLK=64; counted-vmcnt staging =======
__launch_bounds__(512, 1) __global__
void k_attn(const _Float16* __restrict__ Qb, const _Float16* __restrict__ Kb,
            const _Float16* __restrict__ VT, const _Float16* __restrict__ WoT,
            const float* __restrict__ bout, float* __restrict__ Out) {
    extern __shared__ __align__(16) char smem[];
    char* buf[2] = { smem, smem + 49152 };
    char* Pl = smem + 98304;
    float* Mp = (float*)(smem + 123904);
    float* Lp = (float*)(smem + 124928);

    const int tid = threadIdx.x, w = tid >> 6, lane = tid & 63, g = lane >> 4, f = lane & 15;
    const int rh = w >> 2, kh = w & 3;
    const int bid = blockIdx.x;
    const int swzb = (bid & 7) * 32 + (bid >> 3);
    const int b = swzb >> 6, qt = swzb & 63;
    const int q0 = qt * 64, kbase = q0 - 64;
    const long bofs = (long)b * SEQ;

    f16x8 qf[2][16];
#pragma unroll
    for (int mt = 0; mt < 2; ++mt) {
        const _Float16* qr = Qb + (bofs + q0 + rh * 32 + mt * 16 + f) * EMB + g * 8;
#pragma unroll
        for (int ks = 0; ks < 16; ++ks) qf[mt][ks] = *(const f16x8*)(qr + ks * 32);
    }

    auto stageK = [&](int ec, char* dst) {
#pragma unroll
        for (int it = 0; it < 6; ++it) {
            int slot = it * 512 + tid;
            int r = slot >> 4, c = slot & 15;
            int cs = c ^ (r & 7);
            int key = min(max(kbase + r, 0), SEQ - 1);
            gl_lds16(Kb + (bofs + key) * EMB + ec * 128 + cs * 8, dst + slot * 16);
        }
    };
    auto stageVT = [&](int ec, char* dst) {
#pragma unroll
        for (int it = 0; it < 6; ++it) {
            int slot = it * 512 + tid;
            int r = slot / 24, c = slot - r * 24;
            int cs = c ^ (r & 7);
            int k0 = min(max(kbase + cs * 8, 0), SEQ - 8);
            gl_lds16(VT + ((long)b * 512 + ec * 128 + r) * 4096 + k0, dst + slot * 16);
        }
    };

    f32x4 sacc[2][3] = {};
    stageK(0, buf[0]);
    for (int ec = 0; ec < 4; ++ec) {
        if (ec < 3) stageK(ec + 1, buf[(ec + 1) & 1]);
        else stageVT(0, buf[0]);
        VMW(6);
        BARRIER();
        const char* kb = buf[ec & 1];
#pragma unroll
        for (int kk = 0; kk < 4; ++kk) {
#pragma unroll
            for (int t = 0; t < 3; ++t) {
                int n = kh * 48 + t * 16 + f;
                f16x8 bf = *(const f16x8*)(kb + n * 256 + (((kk * 4 + g) ^ (n & 7)) << 4));
#pragma unroll
                for (int mt = 0; mt < 2; ++mt)
                    sacc[mt][t] = MFMA(qf[mt][ec * 4 + kk], bf, sacc[mt][t]);
            }
        }
        BARRIER();
    }

    float m[2][4] = {{-3e30f, -3e30f, -3e30f, -3e30f}, {-3e30f, -3e30f, -3e30f, -3e30f}};
    float l[2][4] = {};
#pragma unroll
    for (int mt = 0; mt < 2; ++mt)
#pragma unroll
        for (int t = 0; t < 3; ++t) {
            int key = kbase + kh * 48 + t * 16 + f;
            bool kv = (key >= 0) && (key < SEQ);
#pragma unroll
            for (int j = 0; j < 4; ++j) {
                int d = key - (q0 + rh * 32 + mt * 16 + g * 4 + j);
                bool valid = kv && (d >= -64) && (d <= 64);
                float s = valid ? sacc[mt][t][j] : -3e30f;
                sacc[mt][t][j] = s;
                m[mt][j] = fmaxf(m[mt][j], s);
            }
        }
#pragma unroll
    for (int mt = 0; mt < 2; ++mt)
#pragma unroll
        for (int j = 0; j < 4; ++j) {
            m[mt][j] = fmaxf(m[mt][j], __shfl_xor(m[mt][j], 1));
            m[mt][j] = fmaxf(m[mt][j], __shfl_xor(m[mt][j], 2));
            m[mt][j] = fmaxf(m[mt][j], __shfl_xor(m[mt][j], 4));
            m[mt][j] = fmaxf(m[mt][j], __shfl_xor(m[mt][j], 8));
        }
    if (f == 0) {
#pragma unroll
        for (int mt = 0; mt < 2; ++mt)
#pragma unroll
            for (int j = 0; j < 4; ++j)
                Mp[kh * 64 + rh * 32 + mt * 16 + g * 4 + j] = m[mt][j];
    }
    __syncthreads();
#pragma unroll
    for (int mt = 0; mt < 2; ++mt)
#pragma unroll
        for (int j = 0; j < 4; ++j) {
            int r = rh * 32 + mt * 16 + g * 4 + j;
            m[mt][j] = fmaxf(fmaxf(Mp[r], Mp[64 + r]), fmaxf(Mp[128 + r], Mp[192 + r]));
        }
#pragma unroll
    for (int mt = 0; mt < 2; ++mt)
#pragma unroll
        for (int t = 0; t < 3; ++t)
#pragma unroll
            for (int j = 0; j < 4; ++j) {
                float p = __expf(sacc[mt][t][j] - m[mt][j]);
                sacc[mt][t][j] = p;
                l[mt][j] += p;
            }
#pragma unroll
    for (int mt = 0; mt < 2; ++mt)
#pragma unroll
        for (int j = 0; j < 4; ++j) {
            l[mt][j] += __shfl_xor(l[mt][j], 1);
            l[mt][j] += __shfl_xor(l[mt][j], 2);
            l[mt][j] += __shfl_xor(l[mt][j], 4);
            l[mt][j] += __shfl_xor(l[mt][j], 8);
        }
    if (f == 0) {
#pragma unroll
        for (int mt = 0; mt < 2; ++mt)
#pragma unroll
            for (int j = 0; j < 4; ++j)
                Lp[kh * 64 + rh * 32 + mt * 16 + g * 4 + j] = l[mt][j];
    }
#pragma unroll
    for (int mt = 0; mt < 2; ++mt)
#pragma unroll
        for (int t = 0; t < 3; ++t)
#pragma unroll
            for (int j = 0; j < 4; ++j)
                *(_Float16*)(Pl + (rh * 32 + mt * 16 + g * 4 + j) * 400 +
                             (kh * 48 + t * 16 + f) * 2) = (_Float16)sacc[mt][t][j];
    __syncthreads();

    float rl[2][4];
#pragma unroll
    for (int mt = 0; mt < 2; ++mt)
#pragma unroll
        for (int j = 0; j < 4; ++j) {
            int r = rh * 32 + mt * 16 + g * 4 + j;
            rl[mt][j] = 1.0f / (Lp[r] + Lp[64 + r] + Lp[128 + r] + Lp[192 + r]);
        }

    f16x8 pf[2][6];
#pragma unroll
    for (int mt = 0; mt < 2; ++mt)
#pragma unroll
        for (int kc = 0; kc < 6; ++kc)
            pf[mt][kc] = *(const f16x8*)(Pl + (rh * 32 + mt * 16 + f) * 400 + kc * 64 + g * 16);

    f32x4 oacc[4][2][2] = {};
    for (int ec = 0; ec < 4; ++ec) {
        if (ec < 3) stageVT(ec + 1, buf[(ec + 1) & 1]);
        if (ec > 0) { if (ec < 3) { VMW(6); } else { VMW(0); } }
        BARRIER();
        const char* vb = buf[ec & 1];
#pragma unroll
        for (int kc = 0; kc < 6; ++kc) {
#pragma unroll
            for (int nt = 0; nt < 2; ++nt) {
                int e = kh * 32 + nt * 16 + f;
                f16x8 vf = *(const f16x8*)(vb + e * 384 + (((kc * 4 + g) ^ (e & 7)) << 4));
#pragma unroll
                for (int mt = 0; mt < 2; ++mt)
                    oacc[ec][mt][nt] = MFMA(pf[mt][kc], vf, oacc[ec][mt][nt]);
            }
        }
        BARRIER();
    }

    __syncthreads();
    char* att = smem;
    char* wb0 = smem + 65536;
    char* wb1 = smem + 98304;

    auto stageW = [&](int u, char* dst) {
#pragma unroll
        for (int i = 0; i < 4; ++i) {
            int s = i * 512 + tid;
            int col = s >> 2, ch = s & 3;
            int gd = (ch - (col >> 1)) & 3;
            gl_lds16(WoT + (long)col * 512 + u * 32 + gd * 8, dst + s * 16);
        }
    };
    stageW(0, wb0);
    stageW(1, wb1);
#pragma unroll
    for (int ec = 0; ec < 4; ++ec)
#pragma unroll
        for (int mt = 0; mt < 2; ++mt)
#pragma unroll
            for (int nt = 0; nt < 2; ++nt)
#pragma unroll
                for (int j = 0; j < 4; ++j) {
                    int row = rh * 32 + mt * 16 + g * 4 + j;
                    int col = ec * 128 + kh * 32 + nt * 16 + f;
                    *(_Float16*)(att + row * 1024 + ((col * 2) ^ ((row & 7) << 4))) =
                        (_Float16)(oacc[ec][mt][nt][j] * rl[mt][j]);
                }
    __syncthreads();

    float bv2[8];
#pragma unroll
    for (int nt = 0; nt < 8; ++nt) bv2[nt] = bout[kh * 128 + nt * 16 + f];

    f32x4 acc2[2][8] = {};
    for (int u = 0; u < 16; ++u) {
        const char* wcur = (u & 1) ? wb1 : wb0;
        f16x8 a2[2];
#pragma unroll
        for (int mt = 0; mt < 2; ++mt) {
            int row = rh * 32 + mt * 16 + f;
            a2[mt] = *(const f16x8*)(att + row * 1024 + ((u * 64 + g * 16) ^ ((row & 7) << 4)));
        }
        __builtin_amdgcn_s_setprio(1);
#pragma unroll
        for (int nt = 0; nt < 8; ++nt) {
            int col = kh * 128 + nt * 16 + f;
            f16x8 b2 = *(const f16x8*)(wcur + col * 64 + (((g + (col >> 1)) & 3) << 4));
#pragma unroll
            for (int mt = 0; mt < 2; ++mt)
                acc2[mt][nt] = MFMA(a2[mt], b2, acc2[mt][nt]);
        }
        __builtin_amdgcn_s_setprio(0);
        BARRIER();
        if (u + 2 < 16) {
            stageW(u + 2, (u & 1) ? wb1 : wb0);
            VMW(4);
        } else {
            VMW(0);
        }
        BARRIER();
    }

#pragma unroll
    for (int mt = 0; mt < 2; ++mt)
#pragma unroll
        for (int nt = 0; nt < 8; ++nt) {
            long r0 = bofs + q0 + rh * 32 + mt * 16 + g * 4;
            int c = kh * 128 + nt * 16 + f;
#pragma unroll
            for (int j = 0; j < 4; ++j)
                Out[(r0 + j) * 512 + c] = acc2[mt][nt][j] + bv2[nt];
        }
}

extern "C" void kernel_launch(void* const* d_in, const int* in_sizes, int n_in,
                              void* d_out, int out_size, void* d_ws, size_t ws_size,
                              hipStream_t stream) {
    const float* x     = (const float*)d_in[0];
    const float* W_qkv = (const float*)d_in[1];
    const float* b_qkv = (const float*)d_in[2];
    const float* W_out = (const float*)d_in[3];
    const float* b_out = (const float*)d_in[4];

    char* ws = (char*)d_ws;
    _Float16* xb    = (_Float16*)(ws);                         // 16 MiB
    _Float16* WqkvT = (_Float16*)(ws + 16777216);              // 1.5 MiB
    _Float16* WoutT = (_Float16*)(ws + 16777216 + 1572864);    // 0.5 MiB
    _Float16* Qb    = (_Float16*)(ws + 18874368);              // 16 MiB
    _Float16* Kb    = (_Float16*)(ws + 18874368 + 16777216);   // 16 MiB
    _Float16* VT    = (_Float16*)(ws + 18874368 + 33554432);   // 16 MiB [b][e][k]
    float* out = (float*)d_out;

    (void)hipFuncSetAttribute((const void*)k_gemm_qkv,
                              hipFuncAttributeMaxDynamicSharedMemorySize, 98304);
    (void)hipFuncSetAttribute((const void*)k_attn,
                              hipFuncAttributeMaxDynamicSharedMemorySize, 131072);

    k_prep<<<4352, 256, 0, stream>>>(x, xb, W_qkv, WqkvT, W_out, WoutT);
    k_gemm_qkv<<<768, 512, 98304, stream>>>(xb, WqkvT, b_qkv, Qb, Kb, VT);
    k_attn<<<256, 512, 131072, stream>>>(Qb, Kb, VT, WoutT, b_out, out);
}

// Round 17
// 79.474 us; speedup vs baseline: 3.1738x; 1.0041x over previous
//
#include <hip/hip_runtime.h>

typedef __attribute__((ext_vector_type(8))) _Float16 f16x8;
typedef __attribute__((ext_vector_type(4))) _Float16 f16x4;
typedef __attribute__((ext_vector_type(4))) float f32x4;
typedef __attribute__((address_space(1))) const char gc_char;
typedef __attribute__((address_space(3))) char ls_char;

#define MFMA(a, b, c) __builtin_amdgcn_mfma_f32_16x16x32_f16((a), (b), (c), 0, 0, 0)
#define FENCE() asm volatile("" ::: "memory")
#define BARRIER() do { FENCE(); __builtin_amdgcn_s_barrier(); FENCE(); } while (0)
#define VMW(n) asm volatile("s_waitcnt vmcnt(" #n ")" ::: "memory")

static constexpr int SEQ = 4096;
static constexpr int EMB = 512;
static constexpr float QSCALE = 0.04419417382415922f; // 1/sqrt(512)

__device__ __forceinline__ void gl_lds16(const void* g, void* l) {
    __builtin_amdgcn_global_load_lds((gc_char*)g, (ls_char*)l, 16, 0, 0);
}

// ---------------- fused prep: cast x + LDS-tiled transpose-cast both W ----------------
__global__ void k_prep(const float* __restrict__ x, _Float16* __restrict__ xb,
                       const float* __restrict__ Wq, _Float16* __restrict__ WqT,
                       const float* __restrict__ Wo, _Float16* __restrict__ WoT) {
    const int bid = blockIdx.x, tid = threadIdx.x;
    if (bid < 4096) {
        long i = (long)bid * 256 + tid;
        const float4* p = (const float4*)x + i * 2;
        float4 a = p[0], b = p[1];
        f16x8 v;
        v[0] = (_Float16)a.x; v[1] = (_Float16)a.y; v[2] = (_Float16)a.z; v[3] = (_Float16)a.w;
        v[4] = (_Float16)b.x; v[5] = (_Float16)b.y; v[6] = (_Float16)b.z; v[7] = (_Float16)b.w;
        *(f16x8*)(xb + i * 8) = v;
    } else {
        __shared__ float Ls[64][65];
        int t = bid - 4096;
        const float* W; _Float16* WT; int N, k0, n0;
        if (t < 192) { W = Wq; WT = WqT; N = 1536; k0 = (t & 7) * 64; n0 = (t >> 3) * 64; }
        else { t -= 192; W = Wo; WT = WoT; N = 512; k0 = (t & 7) * 64; n0 = (t >> 3) * 64; }
        int c = tid & 63, r4 = tid >> 6;
#pragma unroll
        for (int i = 0; i < 16; ++i) {
            int row = i * 4 + r4;
            Ls[row][c] = W[(long)(k0 + row) * N + n0 + c];
        }
        __syncthreads();
#pragma unroll
        for (int i = 0; i < 16; ++i) {
            int row = i * 4 + r4;
            WT[(long)(n0 + row) * 512 + k0 + c] = (_Float16)Ls[c][row];
        }
    }
}

// ================= 128x256 tile, BK=64, 4-phase counted-vmcnt QKV GEMM =================
__launch_bounds__(512, 1) __global__
void k_gemm_qkv(const _Float16* __restrict__ A, const _Float16* __restrict__ BT,
                const float* __restrict__ bias,
                _Float16* __restrict__ Qo, _Float16* __restrict__ Ko, _Float16* __restrict__ VT) {
    extern __shared__ __align__(16) char smem[];
    const int tid = threadIdx.x, lane = tid & 63, w = tid >> 6, g = lane >> 4, f = lane & 15;
    const int wrow = w >> 2, wcol = w & 3;
    const int bid = blockIdx.x;
    const int swz = (bid & 7) * 96 + (bid >> 3);
    const int brow = swz / 6, bcol = swz - brow * 6;
    const long row0 = (long)brow * 128;
    const int col0 = bcol * 256;
    const char* Abase = (const char*)A + row0 * 1024;
    const char* Bbase = (const char*)BT + (long)col0 * 1024;

    f32x4 acc[4][4] = {};
    f16x8 a[2][2], breg[2][2][2];

    auto stageA = [&](int h, char* dst, int kt) {
        int rr = tid >> 3;
        int ch = (tid & 7) ^ (rr & 7);
        int grow = h * 32 + (rr & 31) + (rr >> 5) * 64;
        gl_lds16(Abase + (long)grow * 1024 + kt * 128 + ch * 16, dst + h * 8192 + tid * 16);
    };
    auto stageB = [&](int h, char* dst, int kt) {
#pragma unroll
        for (int it = 0; it < 2; ++it) {
            int s = it * 512 + tid;
            int cc = s >> 3;
            int ch = (s & 7) ^ (cc & 7);
            int gcol = h * 32 + (cc & 31) + (cc >> 5) * 64;
            gl_lds16(Bbase + (long)gcol * 1024 + kt * 128 + ch * 16,
                     dst + 16384 + h * 16384 + s * 16);
        }
    };
    auto ldA = [&](const char* buf, int mh) {
#pragma unroll
        for (int mi = 0; mi < 2; ++mi)
#pragma unroll
            for (int ks = 0; ks < 2; ++ks) {
                int rr = wrow * 32 + mi * 16 + f;
                int cl = ks * 4 + g;
                a[mi][ks] = *(const f16x8*)(buf + mh * 8192 + rr * 128 + ((cl ^ (rr & 7)) << 4));
            }
    };
    auto ldB = [&](const char* buf, int nh) {
#pragma unroll
        for (int ni = 0; ni < 2; ++ni)
#pragma unroll
            for (int ks = 0; ks < 2; ++ks) {
                int cc = wcol * 32 + ni * 16 + f;
                int cl = ks * 4 + g;
                breg[nh][ni][ks] =
                    *(const f16x8*)(buf + 16384 + nh * 16384 + cc * 128 + ((cl ^ (cc & 7)) << 4));
            }
    };
    auto mfma8 = [&](int mh, int nh) {
        __builtin_amdgcn_s_setprio(1);
#pragma unroll
        for (int mi = 0; mi < 2; ++mi)
#pragma unroll
            for (int ni = 0; ni < 2; ++ni)
#pragma unroll
                for (int ks = 0; ks < 2; ++ks)
                    acc[mh * 2 + mi][nh * 2 + ni] =
                        MFMA(a[mi][ks], breg[nh][ni][ks], acc[mh * 2 + mi][nh * 2 + ni]);
        __builtin_amdgcn_s_setprio(0);
    };

    stageB(0, smem, 0);
    stageA(0, smem, 0); stageA(1, smem, 0);
    stageB(1, smem, 0);
    VMW(3);
    BARRIER();

    for (int kt = 0; kt < 8; ++kt) {
        const char* cur = smem + (kt & 1) * 49152;
        char* nxt = smem + ((kt + 1) & 1) * 49152;
        const bool last = (kt == 7);
        ldA(cur, 0); ldB(cur, 0);
        if (!last) stageB(0, nxt, kt + 1);
        BARRIER();
        mfma8(0, 0);
        if (!last) { VMW(2); } else { VMW(0); }
        BARRIER();
        ldB(cur, 1);
        if (!last) { stageA(0, nxt, kt + 1); stageA(1, nxt, kt + 1); }
        BARRIER();
        mfma8(0, 1);
        BARRIER();
        ldA(cur, 1);
        if (!last) stageB(1, nxt, kt + 1);
        BARRIER();
        mfma8(1, 0);
        BARRIER();
        mfma8(1, 1);
        if (!last) { VMW(3); }
        BARRIER();
    }

    float bv[4];
#pragma unroll
    for (int ni = 0; ni < 4; ++ni) bv[ni] = bias[col0 + wcol * 64 + ni * 16 + f];

    if (col0 >= 1024) {
#pragma unroll
        for (int mi = 0; mi < 4; ++mi)
#pragma unroll
            for (int ni = 0; ni < 4; ++ni) {
                int r0 = wrow * 64 + mi * 16 + g * 4;
                int c = wcol * 64 + ni * 16 + f;
                f16x4 v4;
#pragma unroll
                for (int j = 0; j < 4; ++j) v4[j] = (_Float16)(acc[mi][ni][j] + bv[ni]);
                *(f16x4*)(smem + c * 256 + ((r0 * 2) ^ ((c & 7) << 4))) = v4;
            }
        __syncthreads();
        int bb = (int)(row0 >> 12);
        _Float16* vt = VT + ((long)bb * 512 + (col0 - 1024)) * 4096 + (row0 & 4095);
#pragma unroll
        for (int it = 0; it < 8; ++it) {
            int slot = it * 512 + tid;
            int e = slot >> 4, ch = slot & 15;
            f16x8 v = *(const f16x8*)(smem + e * 256 + ((ch * 16) ^ ((e & 7) << 4)));
            *(f16x8*)(vt + (long)e * 4096 + ch * 8) = v;
        }
    } else {
        const float sc = (col0 < 512) ? QSCALE : 1.0f;
#pragma unroll
        for (int mi = 0; mi < 4; ++mi)
#pragma unroll
            for (int ni = 0; ni < 4; ++ni)
#pragma unroll
                for (int j = 0; j < 4; ++j) {
                    int r = wrow * 64 + mi * 16 + g * 4 + j;
                    int c = wcol * 64 + ni * 16 + f;
                    float v = (acc[mi][ni][j] + bv[ni]) * sc;
                    int pc = ((c >> 3) + ((r >> 2) & 7) * 2) & 31;
                    *(_Float16*)(smem + r * 512 + pc * 16 + (c & 7) * 2) = (_Float16)v;
                }
        __syncthreads();
        _Float16* dst = (col0 < 512) ? Qo : Ko;
        int cofs = (col0 < 512) ? col0 : col0 - 512;
#pragma unroll
        for (int it = 0; it < 8; ++it) {
            int slot = it * 512 + tid;
            int r = slot >> 5, ch = slot & 31;
            int pc = (ch + ((r >> 2) & 7) * 2) & 31;
            f16x8 v = *(const f16x8*)(smem + r * 512 + pc * 16);
            *(f16x8*)(dst + (row0 + r) * 512 + cofs + ch * 8) = v;
        }
    }
}

// ======= fused attention + out-proj: QBLK=64; phase-2 = 3-buffer W rotation (T14) =======
__launch_bounds__(512, 1) __global__
void k_attn(const _Float16* __restrict__ Qb, const _Float16* __restrict__ Kb,
            const _Float16* __restrict__ VT, const _Float16* __restrict__ WoT,
            const float* __restrict__ bout, float* __restrict__ Out) {
    extern __shared__ __align__(16) char smem[];
    char* Pl = smem + 98304;
    float* Mp = (float*)(smem + 123904);
    float* Lp = (float*)(smem + 124928);

    const int tid = threadIdx.x, w = tid >> 6, lane = tid & 63, g = lane >> 4, f = lane & 15;
    const int rh = w >> 2, kh = w & 3;
    const int bid = blockIdx.x;
    const int swzb = (bid & 7) * 32 + (bid >> 3);
    const int b = swzb >> 6, qt = swzb & 63;
    const int q0 = qt * 64, kbase = q0 - 64;
    const long bofs = (long)b * SEQ;

    f16x8 qf[2][16];
#pragma unroll
    for (int mt = 0; mt < 2; ++mt) {
        const _Float16* qr = Qb + (bofs + q0 + rh * 32 + mt * 16 + f) * EMB + g * 8;
#pragma unroll
        for (int ks = 0; ks < 16; ++ks) qf[mt][ks] = *(const f16x8*)(qr + ks * 32);
    }

    auto stageK = [&](int ec, char* dst) {
#pragma unroll
        for (int it = 0; it < 6; ++it) {
            int slot = it * 512 + tid;
            int r = slot >> 4, c = slot & 15;
            int cs = c ^ (r & 7);
            int key = min(max(kbase + r, 0), SEQ - 1);
            gl_lds16(Kb + (bofs + key) * EMB + ec * 128 + cs * 8, dst + slot * 16);
        }
    };
    auto stageVT = [&](int ec, char* dst) {
#pragma unroll
        for (int it = 0; it < 6; ++it) {
            int slot = it * 512 + tid;
            int r = slot / 24, c = slot - r * 24;
            int cs = c ^ (r & 7);
            int k0 = min(max(kbase + cs * 8, 0), SEQ - 8);
            gl_lds16(VT + ((long)b * 512 + ec * 128 + r) * 4096 + k0, dst + slot * 16);
        }
    };

    f32x4 sacc[2][3] = {};
    stageK(0, smem);
    for (int ec = 0; ec < 4; ++ec) {
        if (ec < 3) stageK(ec + 1, smem + ((ec + 1) & 1) * 49152);
        else stageVT(0, smem);
        VMW(6);
        BARRIER();
        const char* kb = smem + (ec & 1) * 49152;
#pragma unroll
        for (int kk = 0; kk < 4; ++kk) {
#pragma unroll
            for (int t = 0; t < 3; ++t) {
                int n = kh * 48 + t * 16 + f;
                f16x8 bf = *(const f16x8*)(kb + n * 256 + (((kk * 4 + g) ^ (n & 7)) << 4));
#pragma unroll
                for (int mt = 0; mt < 2; ++mt)
                    sacc[mt][t] = MFMA(qf[mt][ec * 4 + kk], bf, sacc[mt][t]);
            }
        }
        BARRIER();
    }

    float m[2][4] = {{-3e30f, -3e30f, -3e30f, -3e30f}, {-3e30f, -3e30f, -3e30f, -3e30f}};
    float l[2][4] = {};
#pragma unroll
    for (int mt = 0; mt < 2; ++mt)
#pragma unroll
        for (int t = 0; t < 3; ++t) {
            int key = kbase + kh * 48 + t * 16 + f;
            bool kv = (key >= 0) && (key < SEQ);
#pragma unroll
            for (int j = 0; j < 4; ++j) {
                int d = key - (q0 + rh * 32 + mt * 16 + g * 4 + j);
                bool valid = kv && (d >= -64) && (d <= 64);
                float s = valid ? sacc[mt][t][j] : -3e30f;
                sacc[mt][t][j] = s;
                m[mt][j] = fmaxf(m[mt][j], s);
            }
        }
#pragma unroll
    for (int mt = 0; mt < 2; ++mt)
#pragma unroll
        for (int j = 0; j < 4; ++j) {
            m[mt][j] = fmaxf(m[mt][j], __shfl_xor(m[mt][j], 1));
            m[mt][j] = fmaxf(m[mt][j], __shfl_xor(m[mt][j], 2));
            m[mt][j] = fmaxf(m[mt][j], __shfl_xor(m[mt][j], 4));
            m[mt][j] = fmaxf(m[mt][j], __shfl_xor(m[mt][j], 8));
        }
    if (f == 0) {
#pragma unroll
        for (int mt = 0; mt < 2; ++mt)
#pragma unroll
            for (int j = 0; j < 4; ++j)
                Mp[kh * 64 + rh * 32 + mt * 16 + g * 4 + j] = m[mt][j];
    }
    __syncthreads();
#pragma unroll
    for (int mt = 0; mt < 2; ++mt)
#pragma unroll
        for (int j = 0; j < 4; ++j) {
            int r = rh * 32 + mt * 16 + g * 4 + j;
            m[mt][j] = fmaxf(fmaxf(Mp[r], Mp[64 + r]), fmaxf(Mp[128 + r], Mp[192 + r]));
        }
#pragma unroll
    for (int mt = 0; mt < 2; ++mt)
#pragma unroll
        for (int t = 0; t < 3; ++t)
#pragma unroll
            for (int j = 0; j < 4; ++j) {
                float p = __expf(sacc[mt][t][j] - m[mt][j]);
                sacc[mt][t][j] = p;
                l[mt][j] += p;
            }
#pragma unroll
    for (int mt = 0; mt < 2; ++mt)
#pragma unroll
        for (int j = 0; j < 4; ++j) {
            l[mt][j] += __shfl_xor(l[mt][j], 1);
            l[mt][j] += __shfl_xor(l[mt][j], 2);
            l[mt][j] += __shfl_xor(l[mt][j], 4);
            l[mt][j] += __shfl_xor(l[mt][j], 8);
        }
    if (f == 0) {
#pragma unroll
        for (int mt = 0; mt < 2; ++mt)
#pragma unroll
            for (int j = 0; j < 4; ++j)
                Lp[kh * 64 + rh * 32 + mt * 16 + g * 4 + j] = l[mt][j];
    }
#pragma unroll
    for (int mt = 0; mt < 2; ++mt)
#pragma unroll
        for (int t = 0; t < 3; ++t)
#pragma unroll
            for (int j = 0; j < 4; ++j)
                *(_Float16*)(Pl + (rh * 32 + mt * 16 + g * 4 + j) * 400 +
                             (kh * 48 + t * 16 + f) * 2) = (_Float16)sacc[mt][t][j];
    __syncthreads();

    float rl[2][4];
#pragma unroll
    for (int mt = 0; mt < 2; ++mt)
#pragma unroll
        for (int j = 0; j < 4; ++j) {
            int r = rh * 32 + mt * 16 + g * 4 + j;
            rl[mt][j] = 1.0f / (Lp[r] + Lp[64 + r] + Lp[128 + r] + Lp[192 + r]);
        }

    f16x8 pf[2][6];
#pragma unroll
    for (int mt = 0; mt < 2; ++mt)
#pragma unroll
        for (int kc = 0; kc < 6; ++kc)
            pf[mt][kc] = *(const f16x8*)(Pl + (rh * 32 + mt * 16 + f) * 400 + kc * 64 + g * 16);

    f32x4 oacc[4][2][2] = {};
    for (int ec = 0; ec < 4; ++ec) {
        if (ec < 3) stageVT(ec + 1, smem + ((ec + 1) & 1) * 49152);
        if (ec > 0) { if (ec < 3) { VMW(6); } else { VMW(0); } }
        BARRIER();
        const char* vb = smem + (ec & 1) * 49152;
#pragma unroll
        for (int kc = 0; kc < 6; ++kc) {
#pragma unroll
            for (int nt = 0; nt < 2; ++nt) {
                int e = kh * 32 + nt * 16 + f;
                f16x8 vf = *(const f16x8*)(vb + e * 384 + (((kc * 4 + g) ^ (e & 7)) << 4));
#pragma unroll
                for (int mt = 0; mt < 2; ++mt)
                    oacc[ec][mt][nt] = MFMA(pf[mt][kc], vf, oacc[ec][mt][nt]);
            }
        }
        BARRIER();
    }

    // ---- phase 2: out-proj with 3-buffer W rotation; stage issued BEFORE MFMA ----
    __syncthreads();
    char* att = smem; // 64 rows x 1024B; W buffers at smem + 65536 + (u%3)*32768

    auto stageW = [&](int u) {
        char* dst = smem + 65536 + (u % 3) * 32768;
#pragma unroll
        for (int i = 0; i < 4; ++i) {
            int s = i * 512 + tid;
            int col = s >> 2, ch = s & 3;
            int gd = (ch - (col >> 1)) & 3;
            gl_lds16(WoT + (long)col * 512 + u * 32 + gd * 8, dst + s * 16);
        }
    };
    stageW(0);
    stageW(1);
#pragma unroll
    for (int ec = 0; ec < 4; ++ec)
#pragma unroll
        for (int mt = 0; mt < 2; ++mt)
#pragma unroll
            for (int nt = 0; nt < 2; ++nt)
#pragma unroll
                for (int j = 0; j < 4; ++j) {
                    int row = rh * 32 + mt * 16 + g * 4 + j;
                    int col = ec * 128 + kh * 32 + nt * 16 + f;
                    *(_Float16*)(att + row * 1024 + ((col * 2) ^ ((row & 7) << 4))) =
                        (_Float16)(oacc[ec][mt][nt][j] * rl[mt][j]);
                }
    __syncthreads(); // att + W units 0,1 resident

    float bv2[8];
#pragma unroll
    for (int nt = 0; nt < 8; ++nt) bv2[nt] = bout[kh * 128 + nt * 16 + f];

    f32x4 acc2[2][8] = {};
    for (int u = 0; u < 16; ++u) {
        const char* wcur = smem + 65536 + (u % 3) * 32768;
        if (u + 2 < 16) stageW(u + 2); // hides under this unit's MFMAs
        f16x8 a2[2];
#pragma unroll
        for (int mt = 0; mt < 2; ++mt) {
            int row = rh * 32 + mt * 16 + f;
            a2[mt] = *(const f16x8*)(att + row * 1024 + ((u * 64 + g * 16) ^ ((row & 7) << 4)));
        }
        __builtin_amdgcn_s_setprio(1);
#pragma unroll
        for (int nt = 0; nt < 8; ++nt) {
            int col = kh * 128 + nt * 16 + f;
            f16x8 b2 = *(const f16x8*)(wcur + col * 64 + (((g + (col >> 1)) & 3) << 4));
#pragma unroll
            for (int mt = 0; mt < 2; ++mt)
                acc2[mt][nt] = MFMA(a2[mt], b2, acc2[mt][nt]);
        }
        __builtin_amdgcn_s_setprio(0);
        if (u < 15) {
            if (u < 14) { VMW(4); } else { VMW(0); } // retire stage(u+1)
            BARRIER();                               // single barrier per unit
        }
    }

#pragma unroll
    for (int mt = 0; mt < 2; ++mt)
#pragma unroll
        for (int nt = 0; nt < 8; ++nt) {
            long r0 = bofs + q0 + rh * 32 + mt * 16 + g * 4;
            int c = kh * 128 + nt * 16 + f;
#pragma unroll
            for (int j = 0; j < 4; ++j)
                Out[(r0 + j) * 512 + c] = acc2[mt][nt][j] + bv2[nt];
        }
}

extern "C" void kernel_launch(void* const* d_in, const int* in_sizes, int n_in,
                              void* d_out, int out_size, void* d_ws, size_t ws_size,
                              hipStream_t stream) {
    const float* x     = (const float*)d_in[0];
    const float* W_qkv = (const float*)d_in[1];
    const float* b_qkv = (const float*)d_in[2];
    const float* W_out = (const float*)d_in[3];
    const float* b_out = (const float*)d_in[4];

    char* ws = (char*)d_ws;
    _Float16* xb    = (_Float16*)(ws);                         // 16 MiB
    _Float16* WqkvT = (_Float16*)(ws + 16777216);              // 1.5 MiB
    _Float16* WoutT = (_Float16*)(ws + 16777216 + 1572864);    // 0.5 MiB
    _Float16* Qb    = (_Float16*)(ws + 18874368);              // 16 MiB
    _Float16* Kb    = (_Float16*)(ws + 18874368 + 16777216);   // 16 MiB
    _Float16* VT    = (_Float16*)(ws + 18874368 + 33554432);   // 16 MiB [b][e][k]
    float* out = (float*)d_out;

    (void)hipFuncSetAttribute((const void*)k_gemm_qkv,
                              hipFuncAttributeMaxDynamicSharedMemorySize, 98304);
    (void)hipFuncSetAttribute((const void*)k_attn,
                              hipFuncAttributeMaxDynamicSharedMemorySize, 163840);

    k_prep<<<4352, 256, 0, stream>>>(x, xb, W_qkv, WqkvT, W_out, WoutT);
    k_gemm_qkv<<<768, 512, 98304, stream>>>(xb, WqkvT, b_qkv, Qb, Kb, VT);
    k_attn<<<256, 512, 163840, stream>>>(Qb, Kb, VT, WoutT, b_out, out);
}